// Round 6
// baseline (572.248 us; speedup 1.0000x reference)
//
#include <hip/hip_runtime.h>
#include <hip/hip_bf16.h>

#define NB 32
#define NN 128
#define NE 16256
#define ND 64
#define NHID 128
#define NM 128
#define NOH 256
#define NT 2
#define EHALF 8128
#define NTILE 127        // 64-edge tiles per half (127*64 == 8128 exactly)
#define TILE_E 64

typedef short s16x8 __attribute__((ext_vector_type(8)));
typedef short s16x4 __attribute__((ext_vector_type(4)));
typedef float f32x4 __attribute__((ext_vector_type(4)));

#define MFMA16(a, b, c) __builtin_amdgcn_mfma_f32_16x16x32_bf16((a), (b), (c), 0, 0, 0)

// ---- ws layout (bytes) ----
// partial: bf16 [256][m=128][n=128]
#define PARTIAL_SZ ((size_t)256 * 128 * 128 * 2)          //  8,388,608
#define WS_RS      (PARTIAL_SZ)                           // ushort[NE][128]
#define RS_SZ      ((size_t)NE * 128 * 2)                 //  4,161,536
#define WS_RRT     (WS_RS + RS_SZ)                        // ushort[128][NE]
#define RRT_SZ     ((size_t)128 * NE * 2)                 //  4,161,536
#define WS_IWA     (WS_RRT + RRT_SZ)                      // ushort[b][half][it][h=128][n=128]
#define IWA_SZ     ((size_t)NB * 2 * 2 * 128 * 128 * 2)   //  8,388,608
// total = 25.1 MB (<= proven 32 MB)

__device__ __forceinline__ ushort f2bf(float x) {
    uint u = __float_as_uint(x);
    return (ushort)((u + 0x7fffu + ((u >> 16) & 1u)) >> 16);
}
__device__ __forceinline__ float bf2f(ushort h) {
    return __uint_as_float(((uint)h) << 16);
}
__device__ __forceinline__ float4 ldg4(const float* p) {
    return *reinterpret_cast<const float4*>(p);
}
// XOR-swizzle within a row (G4): byte ^= (row&7)<<4
__device__ __forceinline__ char* swz(void* base, int row, int rowBytes, int bir) {
    return (char*)base + row * rowBytes + (bir ^ ((row & 7) << 4));
}
__device__ __forceinline__ const char* swzc(const void* base, int row, int rowBytes, int bir) {
    return (const char*)base + row * rowBytes + (bir ^ ((row & 7) << 4));
}

// ---------------------------------------------------------------------------
// k_pre: fused conversions + inpWA precompute.
// blocks 0..126: rrT transpose+convert; 127..253: rs convert;
// blocks 254..381: inpWA[b][half][it] = (inp[b] @ WA^T) in bf16 [h][n]
// ---------------------------------------------------------------------------
__global__ __launch_bounds__(256)
void k_pre(const float* __restrict__ inputs,
           const float* __restrict__ rel_rec, const float* __restrict__ rel_send,
           const float* __restrict__ w1, const float* __restrict__ w3,
           char* __restrict__ ws)
{
    ushort* rs  = (ushort*)(ws + WS_RS);
    ushort* rrT = (ushort*)(ws + WS_RRT);
    const int t = threadIdx.x;
    const int blk = blockIdx.x;
    __shared__ float lds[128][65];

    if (blk < 127) {                       // rrT: transpose rel_rec -> [n][e] bf16
        const int eb = blk;
        for (int nh = 0; nh < 2; ++nh) {
            __syncthreads();
            for (int i = t; i < 128 * 64; i += 256) {
                int e = i >> 6, n = i & 63;
                lds[e][n] = rel_rec[(size_t)(eb * 128 + e) * 128 + nh * 64 + n];
            }
            __syncthreads();
            for (int i = t; i < 64 * 128; i += 256) {
                int n = i >> 7, e = i & 127;
                rrT[(size_t)(nh * 64 + n) * NE + eb * 128 + e] = f2bf(lds[e][n]);
            }
        }
    } else if (blk < 254) {                // rs: straight convert
        const int eb = blk - 127;
        const float4* src = (const float4*)(rel_send + (size_t)eb * 16384);
        for (int i = t; i < 4096; i += 256) {
            float4 v = src[i];
            ushort4 o;
            o.x = f2bf(v.x); o.y = f2bf(v.y); o.z = f2bf(v.z); o.w = f2bf(v.w);
            *(ushort4*)(rs + (size_t)eb * 16384 + (size_t)i * 4) = o;
        }
    } else {                               // inpWA precompute (MFMA)
        ushort* iwa = (ushort*)(ws + WS_IWA);
        const int wg = blk - 254;          // 0..127
        const int b = wg >> 2, half = (wg >> 1) & 1, it = wg & 1;
        const float* WA  = (half ? w3 : w1) + (size_t)it * NHID * ND;
        const float* inp = inputs + (size_t)b * NN * ND;
        ushort* dst = iwa + (size_t)wg * NHID * NN;    // [h][n]

        const int lane = t & 63, wave = t >> 6;
        const int l16 = lane & 15, l4 = lane >> 4;

        for (int hh = 0; hh < 2; ++hh) {
            const int ht = wave * 2 + hh;
            s16x8 bf[2];
#pragma unroll
            for (int ks = 0; ks < 2; ++ks) {
                const float* p = WA + (size_t)(ht * 16 + l16) * ND + ks * 32 + l4 * 8;
                float4 u = ldg4(p), v = ldg4(p + 4);
                s16x8 f;
                f[0] = (short)f2bf(u.x); f[1] = (short)f2bf(u.y);
                f[2] = (short)f2bf(u.z); f[3] = (short)f2bf(u.w);
                f[4] = (short)f2bf(v.x); f[5] = (short)f2bf(v.y);
                f[6] = (short)f2bf(v.z); f[7] = (short)f2bf(v.w);
                bf[ks] = f;
            }
            for (int nt = 0; nt < 8; ++nt) {
                s16x8 af[2];
#pragma unroll
                for (int ks = 0; ks < 2; ++ks) {
                    const float* p = inp + (size_t)(nt * 16 + l16) * ND + ks * 32 + l4 * 8;
                    float4 u = ldg4(p), v = ldg4(p + 4);
                    s16x8 f;
                    f[0] = (short)f2bf(u.x); f[1] = (short)f2bf(u.y);
                    f[2] = (short)f2bf(u.z); f[3] = (short)f2bf(u.w);
                    f[4] = (short)f2bf(v.x); f[5] = (short)f2bf(v.y);
                    f[6] = (short)f2bf(v.z); f[7] = (short)f2bf(v.w);
                    af[ks] = f;
                }
                f32x4 c = (f32x4){0.f, 0.f, 0.f, 0.f};
                c = MFMA16(af[0], bf[0], c);
                c = MFMA16(af[1], bf[1], c);
                s16x4 o;
                o[0] = (short)f2bf(c[0]); o[1] = (short)f2bf(c[1]);
                o[2] = (short)f2bf(c[2]); o[3] = (short)f2bf(c[3]);
                *(s16x4*)&dst[(size_t)(ht * 16 + l16) * NN + nt * 16 + l4 * 4] = o;
            }
        }
    }
}

// ---------------------------------------------------------------------------
// k_edge: grid 256 = b*8 + half*4 + chunk(4). block 1024 (16 waves, 4/SIMD).
// wave = (wm 0..7, we 0..1): wm owns h/m cols wm*16..; we owns edge rows
// we*32..we*32+31 of each 64-edge tile. agg K=64 split into two K=32 halves,
// merged through LDS in the epilogue. One barrier per tile (round-5 schedule).
// Edge ids are contiguous (indices == arange; relied on since round 2).
// __launch_bounds__ 2nd arg = min BLOCKS/CU on this toolchain => VGPR cap 128.
// ---------------------------------------------------------------------------
__global__ __launch_bounds__(1024, 1)
void k_edge(const float* __restrict__ rel_type,
            const float* __restrict__ b1, const float* __restrict__ b2,
            const float* __restrict__ b3, const float* __restrict__ b4,
            const float* __restrict__ w2, const float* __restrict__ w4,
            char* __restrict__ ws)
{
    const ushort* rsg = (const ushort*)(ws + WS_RS);
    const ushort* rrT = (const ushort*)(ws + WS_RRT);
    const ushort* iwa = (const ushort*)(ws + WS_IWA);
    ushort* partial   = (ushort*)ws;

    const int tid  = threadIdx.x;
    const int wave = tid >> 6;
    const int lane = tid & 63;
    const int l16  = lane & 15;
    const int l4   = lane >> 4;
    const int wm   = wave & 7;
    const int we   = wave >> 3;

    const int wg    = blockIdx.x;
    const int b     = wg >> 3;
    const int half  = (wg >> 2) & 1;
    const int chunk = wg & 3;

    const float* BA    = half ? b3 : b1;
    const float* BB    = half ? b4 : b2;
    const float* WBsrc = half ? w4 : w2;

    __shared__ ushort H_s[2][2][64 * 128];  // 64 KB (buf, it), rows 256B
    __shared__ ushort rs_s[2][64 * 128];    // 32 KB, rows 256B
    __shared__ ushort rr_s[2][128 * 64];    // 32 KB, rows 128B
    __shared__ ushort Mt_s[128 * 64];       // 16 KB, wave-private regions
    __shared__ float  rt_s[2][128];         //  1 KB

    // persistent fragments (~100 VGPR incl. agg)
    s16x8 wIW[2][4];
    const ushort* iwb = iwa + (size_t)((b * 2 + half) * 2) * NHID * NN;
#pragma unroll
    for (int it = 0; it < 2; ++it)
#pragma unroll
        for (int ks = 0; ks < 4; ++ks)
            wIW[it][ks] = *(const s16x8*)(iwb + (size_t)it * NHID * NN +
                                          (size_t)(wm * 16 + l16) * NN + ks * 32 + l4 * 8);
    s16x8 wB[2][4];
#pragma unroll
    for (int it = 0; it < 2; ++it)
#pragma unroll
        for (int ks = 0; ks < 4; ++ks) {
            const float* p = WBsrc + (size_t)(it * NM + wm * 16 + l16) * NHID + ks * 32 + l4 * 8;
            float4 u = ldg4(p), v = ldg4(p + 4);
            s16x8 f;
            f[0] = (short)f2bf(u.x); f[1] = (short)f2bf(u.y);
            f[2] = (short)f2bf(u.z); f[3] = (short)f2bf(u.w);
            f[4] = (short)f2bf(v.x); f[5] = (short)f2bf(v.y);
            f[6] = (short)f2bf(v.z); f[7] = (short)f2bf(v.w);
            wB[it][ks] = f;
        }
    float biasA[2] = {BA[wm * 16 + l16], BA[NHID + wm * 16 + l16]};
    float biasB[2] = {BB[wm * 16 + l16], BB[NM + wm * 16 + l16]};

    f32x4 agg[8];
#pragma unroll
    for (int r = 0; r < 8; ++r) agg[r] = (f32x4){0.f, 0.f, 0.f, 0.f};

    const int t0 = chunk * 32;
    const int t1 = (t0 + 32 < NTILE) ? (t0 + 32) : NTILE;

    // prologue: stage rs(t0) (contiguous edge ids)
    {
        const int e = tid >> 4, c = tid & 15;
        const int ebase0 = half * EHALF + t0 * TILE_E;
        s16x8 v = *(const s16x8*)(rsg + (size_t)(ebase0 + e) * 128 + c * 8);
        *(s16x8*)swz(&rs_s[0][0], e, 256, c * 16) = v;
    }
    __syncthreads();

    for (int t = t0; t < t1; ++t) {
        const int buf  = (t - t0) & 1;
        const int nbuf = buf ^ 1;
        const int ebase = half * EHALF + t * TILE_E;
        const bool do_next = (t + 1) < NTILE;

        // (a) rr load (tile t): 1 vector load / thread
        const int rn = tid >> 3, rc = tid & 7;
        s16x8 rrv = *(const s16x8*)(rrT + (size_t)rn * NE + ebase + rc * 8);

        // (b) rs load (tile t+1): 1 vector load / thread
        const int se = tid >> 4, sc = tid & 15;
        s16x8 rsv;
        if (do_next)
            rsv = *(const s16x8*)(rsg + (size_t)(ebase + TILE_E + se) * 128 + sc * 8);

        // (c) rt stage (tile t), contiguous
        if (tid < 128)
            rt_s[buf][tid] = rel_type[((size_t)b * NE + ebase + (tid >> 1)) * NT + (tid & 1)];

        // (d) H phase: H[it] = relu(RS @ inpWA[it] + bA[it]); rows we*32..+31
#pragma unroll
        for (int eti = 0; eti < 2; ++eti) {
            const int et = we * 2 + eti;
            const int erow = et * 16 + l16;
            s16x8 a0 = *(const s16x8*)swzc(&rs_s[buf][0], erow, 256, (0 * 32 + l4 * 8) * 2);
            s16x8 a1 = *(const s16x8*)swzc(&rs_s[buf][0], erow, 256, (1 * 32 + l4 * 8) * 2);
            s16x8 a2 = *(const s16x8*)swzc(&rs_s[buf][0], erow, 256, (2 * 32 + l4 * 8) * 2);
            s16x8 a3 = *(const s16x8*)swzc(&rs_s[buf][0], erow, 256, (3 * 32 + l4 * 8) * 2);
#pragma unroll
            for (int it = 0; it < 2; ++it) {
                f32x4 c = (f32x4){0.f, 0.f, 0.f, 0.f};
                __builtin_amdgcn_s_setprio(1);
                c = MFMA16(a0, wIW[it][0], c);
                c = MFMA16(a1, wIW[it][1], c);
                c = MFMA16(a2, wIW[it][2], c);
                c = MFMA16(a3, wIW[it][3], c);
                __builtin_amdgcn_s_setprio(0);
#pragma unroll
                for (int r = 0; r < 4; ++r) {
                    const int er = et * 16 + l4 * 4 + r;
                    *(ushort*)swz(&H_s[buf][it][0], er, 256, (wm * 16 + l16) * 2) =
                        f2bf(fmaxf(c[r] + biasA[it], 0.f));
                }
            }
        }

        // (e) LDS staging writes (vmcnt waits covered by H work)
        *(s16x8*)swz(&rr_s[buf][0], rn, 128, rc * 16) = rrv;
        if (do_next)
            *(s16x8*)swz(&rs_s[nbuf][0], se, 256, sc * 16) = rsv;
        __syncthreads();                                   // the ONE barrier

        // (f) Q phase: M (rows we*32..+31) then agg (K-half we)
#pragma unroll
        for (int eti = 0; eti < 2; ++eti) {
            const int et = we * 2 + eti;
            const int e = et * 16 + l16;
            float2 rtv[4];
#pragma unroll
            for (int r = 0; r < 4; ++r)
                rtv[r] = *(const float2*)&rt_s[buf][(et * 16 + l4 * 4 + r) * 2];
            float macc[4] = {0.f, 0.f, 0.f, 0.f};
#pragma unroll
            for (int it = 0; it < 2; ++it) {
                f32x4 c = (f32x4){0.f, 0.f, 0.f, 0.f};
                __builtin_amdgcn_s_setprio(1);
#pragma unroll
                for (int ks = 0; ks < 4; ++ks) {
                    s16x8 a = *(const s16x8*)swzc(&H_s[buf][it][0], e, 256, (ks * 32 + l4 * 8) * 2);
                    c = MFMA16(a, wB[it][ks], c);
                }
                __builtin_amdgcn_s_setprio(0);
#pragma unroll
                for (int r = 0; r < 4; ++r)
                    macc[r] += fmaxf(c[r] + biasB[it], 0.f) * (it ? rtv[r].y : rtv[r].x);
            }
            const int m = wm * 16 + l16;
            s16x4 v;
            v[0] = (short)f2bf(macc[0]);
            v[1] = (short)f2bf(macc[1]);
            v[2] = (short)f2bf(macc[2]);
            v[3] = (short)f2bf(macc[3]);
            *(s16x4*)swz(Mt_s, m, 128, (et * 16 + l4 * 4) * 2) = v;
        }
        {
            const int m = wm * 16 + l16;
            s16x8 bb = *(const s16x8*)swzc(Mt_s, m, 128, (we * 32 + l4 * 8) * 2);
            __builtin_amdgcn_s_setprio(1);
#pragma unroll
            for (int nt = 0; nt < 8; ++nt) {
                s16x8 a = *(const s16x8*)swzc(&rr_s[buf][0], nt * 16 + l16, 128,
                                              (we * 32 + l4 * 8) * 2);
                agg[nt] = MFMA16(a, bb, agg[nt]);
            }
            __builtin_amdgcn_s_setprio(0);
        }
    }

    // ---- epilogue: merge we-halves through LDS (reuse H_s), we==0 stores ----
    __syncthreads();
    float* stash = (float*)&H_s[0][0][0];   // 64 KB = 8 wm * 64 lanes * 32 f32
    if (we == 1) {
#pragma unroll
        for (int nt = 0; nt < 8; ++nt)
            *(f32x4*)&stash[(size_t)(wm * 64 + lane) * 32 + ((nt ^ (lane & 7)) * 4)] = agg[nt];
    }
    __syncthreads();
    if (we == 0) {
        ushort* dst = partial + (size_t)wg * (NN * NM);
        const int m = wm * 16 + l16;
#pragma unroll
        for (int nt = 0; nt < 8; ++nt) {
            f32x4 o = *(const f32x4*)&stash[(size_t)(wm * 64 + lane) * 32 + ((nt ^ (lane & 7)) * 4)];
            o[0] += agg[nt][0]; o[1] += agg[nt][1];
            o[2] += agg[nt][2]; o[3] += agg[nt][3];
            s16x4 v;
            v[0] = (short)f2bf(o[0]);
            v[1] = (short)f2bf(o[1]);
            v[2] = (short)f2bf(o[2]);
            v[3] = (short)f2bf(o[3]);
            *(s16x4*)&dst[(size_t)m * NN + nt * 16 + l4 * 4] = v;
        }
    }
}

// ---------------------------------------------------------------------------
// k_out: reduce 8 bf16 partials -> node MLP 128->256->256->64 + residual
// ---------------------------------------------------------------------------
__global__ __launch_bounds__(256)
void k_out(const ushort* __restrict__ partial,
           const float* __restrict__ inputs,
           const float* __restrict__ ow1, const float* __restrict__ ob1,
           const float* __restrict__ ow2, const float* __restrict__ ob2,
           const float* __restrict__ ow3, const float* __restrict__ ob3,
           float* __restrict__ out)
{
    const int t  = threadIdx.x;
    const int wg = blockIdx.x;      // 0..255
    const int b  = wg >> 3;
    const int n0 = (wg & 7) * 16;

    __shared__ float xr[16 * NM];
    __shared__ float h1[16 * NOH];
    __shared__ float h2[16 * NOH];

    // reduce 8 partials (transposed layout [m][n])
    for (int u = t; u < 512; u += 256) {
        const int m = u >> 2, g = u & 3;
        float s0 = 0.f, s1 = 0.f, s2 = 0.f, s3 = 0.f;
#pragma unroll
        for (int c = 0; c < 8; ++c) {
            const ushort* p = partial + ((size_t)(b * 8 + c)) * (NN * NM) +
                              (size_t)m * NN + n0 + g * 4;
            s16x4 v = *(const s16x4*)p;
            s0 += bf2f((ushort)v[0]); s1 += bf2f((ushort)v[1]);
            s2 += bf2f((ushort)v[2]); s3 += bf2f((ushort)v[3]);
        }
        xr[(g * 4 + 0) * NM + m] = s0;
        xr[(g * 4 + 1) * NM + m] = s1;
        xr[(g * 4 + 2) * NM + m] = s2;
        xr[(g * 4 + 3) * NM + m] = s3;
    }
    __syncthreads();

    {
        float acc[16];
        const float bias = ob1[t];
#pragma unroll
        for (int r = 0; r < 16; ++r) acc[r] = bias;
        const float* wrow = ow1 + (size_t)t * NM;
#pragma unroll 2
        for (int mq = 0; mq < NM / 4; ++mq) {
            const float4 w = ldg4(wrow + mq * 4);
#pragma unroll
            for (int r = 0; r < 16; ++r) {
                const float4 xv = *reinterpret_cast<const float4*>(&xr[r * NM + mq * 4]);
                acc[r] += xv.x * w.x + xv.y * w.y + xv.z * w.z + xv.w * w.w;
            }
        }
#pragma unroll
        for (int r = 0; r < 16; ++r) h1[r * NOH + t] = fmaxf(acc[r], 0.f);
    }
    __syncthreads();

    {
        float acc[16];
        const float bias = ob2[t];
#pragma unroll
        for (int r = 0; r < 16; ++r) acc[r] = bias;
        const float* wrow = ow2 + (size_t)t * NOH;
#pragma unroll 2
        for (int hq = 0; hq < NOH / 4; ++hq) {
            const float4 w = ldg4(wrow + hq * 4);
#pragma unroll
            for (int r = 0; r < 16; ++r) {
                const float4 hv = *reinterpret_cast<const float4*>(&h1[r * NOH + hq * 4]);
                acc[r] += hv.x * w.x + hv.y * w.y + hv.z * w.z + hv.w * w.w;
            }
        }
#pragma unroll
        for (int r = 0; r < 16; ++r) h2[r * NOH + t] = fmaxf(acc[r], 0.f);
    }
    __syncthreads();

    {
        const int d  = t & 63;
        const int rg = t >> 6;
        float acc[4] = {0.f, 0.f, 0.f, 0.f};
        const float* wrow = ow3 + (size_t)d * NOH;
#pragma unroll 2
        for (int hq = 0; hq < NOH / 4; ++hq) {
            const float4 w = ldg4(wrow + hq * 4);
#pragma unroll
            for (int r = 0; r < 4; ++r) {
                const float4 hv = *reinterpret_cast<const float4*>(&h2[(rg * 4 + r) * NOH + hq * 4]);
                acc[r] += hv.x * w.x + hv.y * w.y + hv.z * w.z + hv.w * w.w;
            }
        }
        const float bias = ob3[d];
#pragma unroll
        for (int r = 0; r < 4; ++r) {
            const int n = n0 + rg * 4 + r;
            const size_t idx = ((size_t)b * NN + n) * ND + d;
            out[idx] = inputs[idx] + acc[r] + bias;
        }
    }
}

extern "C" void kernel_launch(void* const* d_in, const int* in_sizes, int n_in,
                              void* d_out, int out_size, void* d_ws, size_t ws_size,
                              hipStream_t stream)
{
    const float* inputs   = (const float*)d_in[0];
    const float* rel_rec  = (const float*)d_in[1];
    const float* rel_send = (const float*)d_in[2];
    const float* rel_type = (const float*)d_in[3];
    const float* w1  = (const float*)d_in[5];
    const float* b1  = (const float*)d_in[6];
    const float* w2  = (const float*)d_in[7];
    const float* b2  = (const float*)d_in[8];
    const float* w3  = (const float*)d_in[9];
    const float* b3  = (const float*)d_in[10];
    const float* w4  = (const float*)d_in[11];
    const float* b4  = (const float*)d_in[12];
    const float* ow1 = (const float*)d_in[13];
    const float* ob1 = (const float*)d_in[14];
    const float* ow2 = (const float*)d_in[15];
    const float* ob2 = (const float*)d_in[16];
    const float* ow3 = (const float*)d_in[17];
    const float* ob3 = (const float*)d_in[18];

    char* ws = (char*)d_ws;

    k_pre <<<dim3(382), dim3(256), 0, stream>>>(inputs, rel_rec, rel_send,
                                                w1, w3, ws);
    k_edge<<<dim3(256), dim3(1024), 0, stream>>>(rel_type,
                                                 b1, b2, b3, b4, w2, w4, ws);
    k_out <<<dim3(256), dim3(256), 0, stream>>>((const ushort*)ws, inputs,
                                                ow1, ob1, ow2, ob2, ow3, ob3,
                                                (float*)d_out);
}

// Round 7
// 205.758 us; speedup vs baseline: 2.7812x; 2.7812x over previous
//
#include <hip/hip_runtime.h>
#include <hip/hip_bf16.h>

#define NB 32
#define NN 128
#define NE 16256
#define ND 64
#define NHID 128
#define NM 128
#define NOH 256
#define NT 2
#define EHALF 8128
#define NTILE 127        // 64-edge tiles per half (127*64 == 8128 exactly)
#define TILE_E 64

typedef short s16x8 __attribute__((ext_vector_type(8)));
typedef short s16x4 __attribute__((ext_vector_type(4)));
typedef float f32x4 __attribute__((ext_vector_type(4)));

#define MFMA16(a, b, c) __builtin_amdgcn_mfma_f32_16x16x32_bf16((a), (b), (c), 0, 0, 0)

// ---- ws layout (bytes) ----
// partial: bf16 [512][m=128][n=128]
#define PARTIAL_SZ ((size_t)512 * 128 * 128 * 2)          // 16,777,216
#define WS_RS      (PARTIAL_SZ)                           // ushort[NE][128]
#define RS_SZ      ((size_t)NE * 128 * 2)                 //  4,161,536
#define WS_RRT     (WS_RS + RS_SZ)                        // ushort[128][NE]
#define RRT_SZ     ((size_t)128 * NE * 2)                 //  4,161,536
#define WS_IWA     (WS_RRT + RRT_SZ)                      // ushort[b][half][it][h=128][n=128]
#define IWA_SZ     ((size_t)NB * 2 * 2 * 128 * 128 * 2)   //  8,388,608
// total = 33,488,896 B (same as round 2 -> proven to fit ws)

__device__ __forceinline__ ushort f2bf(float x) {
    uint u = __float_as_uint(x);
    return (ushort)((u + 0x7fffu + ((u >> 16) & 1u)) >> 16);
}
__device__ __forceinline__ float bf2f(ushort h) {
    return __uint_as_float(((uint)h) << 16);
}
__device__ __forceinline__ float4 ldg4(const float* p) {
    return *reinterpret_cast<const float4*>(p);
}
// XOR-swizzle within a row (G4): byte ^= (row&7)<<4
__device__ __forceinline__ char* swz(void* base, int row, int rowBytes, int bir) {
    return (char*)base + row * rowBytes + (bir ^ ((row & 7) << 4));
}
__device__ __forceinline__ const char* swzc(const void* base, int row, int rowBytes, int bir) {
    return (const char*)base + row * rowBytes + (bir ^ ((row & 7) << 4));
}
// async 16B global->LDS (dest is lane-linear; source pre-swizzled per G21)
__device__ __forceinline__ void gload16(const void* g, void* l) {
    __builtin_amdgcn_global_load_lds(
        (const __attribute__((address_space(1))) void*)g,
        (__attribute__((address_space(3))) void*)l, 16, 0, 0);
}

// ---------------------------------------------------------------------------
// k_pre: fused conversions + inpWA precompute.
// blocks 0..126: rrT transpose+convert; 127..253: rs convert;
// blocks 254..381: inpWA[b][half][it] = (inp[b] @ WA^T) in bf16 [h][n]
// ---------------------------------------------------------------------------
__global__ __launch_bounds__(256)
void k_pre(const float* __restrict__ inputs,
           const float* __restrict__ rel_rec, const float* __restrict__ rel_send,
           const float* __restrict__ w1, const float* __restrict__ w3,
           char* __restrict__ ws)
{
    ushort* rs  = (ushort*)(ws + WS_RS);
    ushort* rrT = (ushort*)(ws + WS_RRT);
    const int t = threadIdx.x;
    const int blk = blockIdx.x;
    __shared__ float lds[128][65];

    if (blk < 127) {                       // rrT: transpose rel_rec -> [n][e] bf16
        const int eb = blk;
        for (int nh = 0; nh < 2; ++nh) {
            __syncthreads();
            for (int i = t; i < 128 * 64; i += 256) {
                int e = i >> 6, n = i & 63;
                lds[e][n] = rel_rec[(size_t)(eb * 128 + e) * 128 + nh * 64 + n];
            }
            __syncthreads();
            for (int i = t; i < 64 * 128; i += 256) {
                int n = i >> 7, e = i & 127;
                rrT[(size_t)(nh * 64 + n) * NE + eb * 128 + e] = f2bf(lds[e][n]);
            }
        }
    } else if (blk < 254) {                // rs: straight convert
        const int eb = blk - 127;
        const float4* src = (const float4*)(rel_send + (size_t)eb * 16384);
        for (int i = t; i < 4096; i += 256) {
            float4 v = src[i];
            ushort4 o;
            o.x = f2bf(v.x); o.y = f2bf(v.y); o.z = f2bf(v.z); o.w = f2bf(v.w);
            *(ushort4*)(rs + (size_t)eb * 16384 + (size_t)i * 4) = o;
        }
    } else {                               // inpWA precompute (MFMA)
        ushort* iwa = (ushort*)(ws + WS_IWA);
        const int wg = blk - 254;          // 0..127
        const int b = wg >> 2, half = (wg >> 1) & 1, it = wg & 1;
        const float* WA  = (half ? w3 : w1) + (size_t)it * NHID * ND;
        const float* inp = inputs + (size_t)b * NN * ND;
        ushort* dst = iwa + (size_t)wg * NHID * NN;    // [h][n]

        const int lane = t & 63, wave = t >> 6;
        const int l16 = lane & 15, l4 = lane >> 4;

        for (int hh = 0; hh < 2; ++hh) {
            const int ht = wave * 2 + hh;
            s16x8 bf[2];
#pragma unroll
            for (int ks = 0; ks < 2; ++ks) {
                const float* p = WA + (size_t)(ht * 16 + l16) * ND + ks * 32 + l4 * 8;
                float4 u = ldg4(p), v = ldg4(p + 4);
                s16x8 f;
                f[0] = (short)f2bf(u.x); f[1] = (short)f2bf(u.y);
                f[2] = (short)f2bf(u.z); f[3] = (short)f2bf(u.w);
                f[4] = (short)f2bf(v.x); f[5] = (short)f2bf(v.y);
                f[6] = (short)f2bf(v.z); f[7] = (short)f2bf(v.w);
                bf[ks] = f;
            }
            for (int nt = 0; nt < 8; ++nt) {
                s16x8 af[2];
#pragma unroll
                for (int ks = 0; ks < 2; ++ks) {
                    const float* p = inp + (size_t)(nt * 16 + l16) * ND + ks * 32 + l4 * 8;
                    float4 u = ldg4(p), v = ldg4(p + 4);
                    s16x8 f;
                    f[0] = (short)f2bf(u.x); f[1] = (short)f2bf(u.y);
                    f[2] = (short)f2bf(u.z); f[3] = (short)f2bf(u.w);
                    f[4] = (short)f2bf(v.x); f[5] = (short)f2bf(v.y);
                    f[6] = (short)f2bf(v.z); f[7] = (short)f2bf(v.w);
                    af[ks] = f;
                }
                f32x4 c = (f32x4){0.f, 0.f, 0.f, 0.f};
                c = MFMA16(af[0], bf[0], c);
                c = MFMA16(af[1], bf[1], c);
                s16x4 o;
                o[0] = (short)f2bf(c[0]); o[1] = (short)f2bf(c[1]);
                o[2] = (short)f2bf(c[2]); o[3] = (short)f2bf(c[3]);
                *(s16x4*)&dst[(size_t)(ht * 16 + l16) * NN + nt * 16 + l4 * 4] = o;
            }
        }
    }
}

// ---------------------------------------------------------------------------
// k_edge: grid 512 = b*16 + half*8 + chunk(8). block 512 (8 waves).
// 73 KB LDS -> 2 blocks/CU (4 waves/SIMD). Two barriers per 64-edge tile:
//  Segment A: issue gload_lds rr(t)->rr_s; stage rt(t); H-phase (read rs_s,
//             write H_s)                                            | bar1
//  Segment B: issue gload_lds rs(t+1)->rs_s; M-phase (read H_s) in two
//             K=32 passes with wave-private Mt roundtrip + agg      | bar2
// All LDS single-buffered (write-after-read separated by the barriers).
// __launch_bounds__(512,2) => VGPR cap 128 (proven clean, rounds 2/5).
// ---------------------------------------------------------------------------
__global__ __launch_bounds__(512, 2)
void k_edge(const float* __restrict__ rel_type,
            const float* __restrict__ b1, const float* __restrict__ b2,
            const float* __restrict__ b3, const float* __restrict__ b4,
            const float* __restrict__ w2, const float* __restrict__ w4,
            char* __restrict__ ws)
{
    const ushort* rsg = (const ushort*)(ws + WS_RS);
    const ushort* rrT = (const ushort*)(ws + WS_RRT);
    const ushort* iwa = (const ushort*)(ws + WS_IWA);
    ushort* partial   = (ushort*)ws;

    const int tid  = threadIdx.x;
    const int wave = tid >> 6;
    const int lane = tid & 63;
    const int l16  = lane & 15;
    const int l4   = lane >> 4;

    const int wg    = blockIdx.x;
    const int b     = wg >> 4;
    const int half  = (wg >> 3) & 1;
    const int chunk = wg & 7;

    const float* BA    = half ? b3 : b1;
    const float* BB    = half ? b4 : b2;
    const float* WBsrc = half ? w4 : w2;

    __shared__ ushort H_s[2][64 * 128];   // 32 KB (it), rows 256B, swz (er&7)<<4
    __shared__ ushort rs_s[64 * 128];     // 16 KB, rows 256B, stored pre-swizzled
    __shared__ ushort rr_s[128 * 64];     // 16 KB, rows 128B, stored pre-swizzled
    __shared__ ushort Mt_s[8][16 * 32];   //  8 KB, wave-private, rows 64B
    __shared__ float  rt_s[128];          // 0.5 KB

    // persistent B-fragments (wIW 32 + wB 32 + agg 32 = 96 VGPR)
    s16x8 wIW[2][4];
    const ushort* iwb = iwa + (size_t)((b * 2 + half) * 2) * NHID * NN;
#pragma unroll
    for (int it = 0; it < 2; ++it)
#pragma unroll
        for (int ks = 0; ks < 4; ++ks)
            wIW[it][ks] = *(const s16x8*)(iwb + (size_t)it * NHID * NN +
                                          (size_t)(wave * 16 + l16) * NN + ks * 32 + l4 * 8);
    s16x8 wB[2][4];
#pragma unroll
    for (int it = 0; it < 2; ++it)
#pragma unroll
        for (int ks = 0; ks < 4; ++ks) {
            const float* p = WBsrc + (size_t)(it * NM + wave * 16 + l16) * NHID + ks * 32 + l4 * 8;
            float4 u = ldg4(p), v = ldg4(p + 4);
            s16x8 f;
            f[0] = (short)f2bf(u.x); f[1] = (short)f2bf(u.y);
            f[2] = (short)f2bf(u.z); f[3] = (short)f2bf(u.w);
            f[4] = (short)f2bf(v.x); f[5] = (short)f2bf(v.y);
            f[6] = (short)f2bf(v.z); f[7] = (short)f2bf(v.w);
            wB[it][ks] = f;
        }
    float biasA[2] = {BA[wave * 16 + l16], BA[NHID + wave * 16 + l16]};
    float biasB[2] = {BB[wave * 16 + l16], BB[NM + wave * 16 + l16]};

    f32x4 agg[8];
#pragma unroll
    for (int r = 0; r < 8; ++r) agg[r] = (f32x4){0.f, 0.f, 0.f, 0.f};

    const int t0 = chunk * 16;
    const int t1 = (t0 + 16 < NTILE) ? (t0 + 16) : NTILE;

    // ---- prologue: stage rs(t0): slot i=(e,c) holds global chunk c^(e&7) ----
    {
        const int ebase0 = half * EHALF + t0 * TILE_E;
#pragma unroll
        for (int s = 0; s < 2; ++s) {
            const int i = s * 512 + tid;
            const int e = i >> 4, c = lane & 15;
            const int cp = c ^ (e & 7);
            gload16(rsg + (size_t)(ebase0 + e) * 128 + cp * 8, (char*)rs_s + i * 16);
        }
    }
    __syncthreads();

    for (int t = t0; t < t1; ++t) {
        const int ebase = half * EHALF + t * TILE_E;
        const bool do_next = (t + 1) < t1;

        // ---- Segment A ----
        // (a) issue rr(t) -> rr_s: slot j=(n,c) holds global chunk c^(n&7)
#pragma unroll
        for (int s = 0; s < 2; ++s) {
            const int j = s * 512 + tid;
            const int n = j >> 3, c = lane & 7;
            const int cp = c ^ (n & 7);
            gload16(rrT + (size_t)n * NE + ebase + cp * 8, (char*)rr_s + j * 16);
        }
        // (b) rt stage (contiguous)
        if (tid < 128)
            rt_s[tid] = rel_type[((size_t)b * NE + ebase + (tid >> 1)) * NT + (tid & 1)];

        // (c) H-phase: H[it] = relu(RS @ inpWA[it] + bA[it])
#pragma unroll
        for (int et = 0; et < 4; ++et) {
            const int erow = et * 16 + l16;
            s16x8 a0 = *(const s16x8*)swzc(rs_s, erow, 256, (0 * 32 + l4 * 8) * 2);
            s16x8 a1 = *(const s16x8*)swzc(rs_s, erow, 256, (1 * 32 + l4 * 8) * 2);
            s16x8 a2 = *(const s16x8*)swzc(rs_s, erow, 256, (2 * 32 + l4 * 8) * 2);
            s16x8 a3 = *(const s16x8*)swzc(rs_s, erow, 256, (3 * 32 + l4 * 8) * 2);
#pragma unroll
            for (int it = 0; it < 2; ++it) {
                f32x4 c = (f32x4){0.f, 0.f, 0.f, 0.f};
                __builtin_amdgcn_s_setprio(1);
                c = MFMA16(a0, wIW[it][0], c);
                c = MFMA16(a1, wIW[it][1], c);
                c = MFMA16(a2, wIW[it][2], c);
                c = MFMA16(a3, wIW[it][3], c);
                __builtin_amdgcn_s_setprio(0);
#pragma unroll
                for (int r = 0; r < 4; ++r) {
                    const int er = et * 16 + l4 * 4 + r;
                    *(ushort*)swz(&H_s[it][0], er, 256, (wave * 16 + l16) * 2) =
                        f2bf(fmaxf(c[r] + biasA[it], 0.f));
                }
            }
        }
        __syncthreads();                                   // bar1

        // ---- Segment B ----
        // (d) issue rs(t+1) -> rs_s (rs(t) fully consumed in segment A)
        if (do_next) {
            const int ebn = ebase + TILE_E;
#pragma unroll
            for (int s = 0; s < 2; ++s) {
                const int i = s * 512 + tid;
                const int e = i >> 4, c = lane & 15;
                const int cp = c ^ (e & 7);
                gload16(rsg + (size_t)(ebn + e) * 128 + cp * 8, (char*)rs_s + i * 16);
            }
        }

        // (e) M + agg in two K=32 passes
        char* mtw = (char*)&Mt_s[wave][0];
#pragma unroll
        for (int p = 0; p < 2; ++p) {
#pragma unroll
            for (int eq = 0; eq < 2; ++eq) {
                const int etq = p * 2 + eq;
                const int e = etq * 16 + l16;
                float2 rtv[4];
#pragma unroll
                for (int r = 0; r < 4; ++r)
                    rtv[r] = *(const float2*)&rt_s[(etq * 16 + l4 * 4 + r) * 2];
                float macc[4] = {0.f, 0.f, 0.f, 0.f};
#pragma unroll
                for (int it = 0; it < 2; ++it) {
                    f32x4 c = (f32x4){0.f, 0.f, 0.f, 0.f};
                    __builtin_amdgcn_s_setprio(1);
#pragma unroll
                    for (int ks = 0; ks < 4; ++ks) {
                        s16x8 a = *(const s16x8*)swzc(&H_s[it][0], e, 256, (ks * 32 + l4 * 8) * 2);
                        c = MFMA16(a, wB[it][ks], c);
                    }
                    __builtin_amdgcn_s_setprio(0);
#pragma unroll
                    for (int r = 0; r < 4; ++r)
                        macc[r] += fmaxf(c[r] + biasB[it], 0.f) * (it ? rtv[r].y : rtv[r].x);
                }
                // Mt write: row l16 (64B), byte (eq*32 + l4*8) ^ ((m&3)<<4)
                s16x4 v;
                v[0] = (short)f2bf(macc[0]);
                v[1] = (short)f2bf(macc[1]);
                v[2] = (short)f2bf(macc[2]);
                v[3] = (short)f2bf(macc[3]);
                *(s16x4*)(mtw + l16 * 64 + ((eq * 32 + l4 * 8) ^ ((l16 & 3) << 4))) = v;
            }
            // B-fragment read (same wave wrote it; DS ops in-order per wave)
            s16x8 bb = *(const s16x8*)(mtw + l16 * 64 + ((l4 * 16) ^ ((l16 & 3) << 4)));
            __builtin_amdgcn_s_setprio(1);
#pragma unroll
            for (int nt = 0; nt < 8; ++nt) {
                const int n = nt * 16 + l16;
                s16x8 a = *(const s16x8*)swzc(rr_s, n, 128, (p * 32 + l4 * 8) * 2);
                agg[nt] = MFMA16(a, bb, agg[nt]);
            }
            __builtin_amdgcn_s_setprio(0);
        }
        __syncthreads();                                   // bar2
    }

    // store bf16 partialT [wg][m][n] (vector s16x4)
    {
        ushort* dst = partial + (size_t)wg * (NN * NM);
        const int m = wave * 16 + l16;
#pragma unroll
        for (int nt = 0; nt < 8; ++nt) {
            s16x4 v;
            v[0] = (short)f2bf(agg[nt][0]);
            v[1] = (short)f2bf(agg[nt][1]);
            v[2] = (short)f2bf(agg[nt][2]);
            v[3] = (short)f2bf(agg[nt][3]);
            *(s16x4*)&dst[(size_t)m * NN + nt * 16 + l4 * 4] = v;
        }
    }
}

// ---------------------------------------------------------------------------
// k_out: reduce 16 bf16 partials -> node MLP 128->256->256->64 + residual
// ---------------------------------------------------------------------------
__global__ __launch_bounds__(256)
void k_out(const ushort* __restrict__ partial,
           const float* __restrict__ inputs,
           const float* __restrict__ ow1, const float* __restrict__ ob1,
           const float* __restrict__ ow2, const float* __restrict__ ob2,
           const float* __restrict__ ow3, const float* __restrict__ ob3,
           float* __restrict__ out)
{
    const int t  = threadIdx.x;
    const int wg = blockIdx.x;      // 0..255
    const int b  = wg >> 3;
    const int n0 = (wg & 7) * 16;

    __shared__ float xr[16 * NM];
    __shared__ float h1[16 * NOH];
    __shared__ float h2[16 * NOH];

    // reduce 16 partials (transposed layout [m][n])
    for (int u = t; u < 512; u += 256) {
        const int m = u >> 2, g = u & 3;
        float s0 = 0.f, s1 = 0.f, s2 = 0.f, s3 = 0.f;
#pragma unroll
        for (int c = 0; c < 16; ++c) {
            const ushort* p = partial + ((size_t)(b * 16 + c)) * (NN * NM) +
                              (size_t)m * NN + n0 + g * 4;
            s16x4 v = *(const s16x4*)p;
            s0 += bf2f((ushort)v[0]); s1 += bf2f((ushort)v[1]);
            s2 += bf2f((ushort)v[2]); s3 += bf2f((ushort)v[3]);
        }
        xr[(g * 4 + 0) * NM + m] = s0;
        xr[(g * 4 + 1) * NM + m] = s1;
        xr[(g * 4 + 2) * NM + m] = s2;
        xr[(g * 4 + 3) * NM + m] = s3;
    }
    __syncthreads();

    {
        float acc[16];
        const float bias = ob1[t];
#pragma unroll
        for (int r = 0; r < 16; ++r) acc[r] = bias;
        const float* wrow = ow1 + (size_t)t * NM;
#pragma unroll 2
        for (int mq = 0; mq < NM / 4; ++mq) {
            const float4 w = ldg4(wrow + mq * 4);
#pragma unroll
            for (int r = 0; r < 16; ++r) {
                const float4 xv = *reinterpret_cast<const float4*>(&xr[r * NM + mq * 4]);
                acc[r] += xv.x * w.x + xv.y * w.y + xv.z * w.z + xv.w * w.w;
            }
        }
#pragma unroll
        for (int r = 0; r < 16; ++r) h1[r * NOH + t] = fmaxf(acc[r], 0.f);
    }
    __syncthreads();

    {
        float acc[16];
        const float bias = ob2[t];
#pragma unroll
        for (int r = 0; r < 16; ++r) acc[r] = bias;
        const float* wrow = ow2 + (size_t)t * NOH;
#pragma unroll 2
        for (int hq = 0; hq < NOH / 4; ++hq) {
            const float4 w = ldg4(wrow + hq * 4);
#pragma unroll
            for (int r = 0; r < 16; ++r) {
                const float4 hv = *reinterpret_cast<const float4*>(&h1[r * NOH + hq * 4]);
                acc[r] += hv.x * w.x + hv.y * w.y + hv.z * w.z + hv.w * w.w;
            }
        }
#pragma unroll
        for (int r = 0; r < 16; ++r) h2[r * NOH + t] = fmaxf(acc[r], 0.f);
    }
    __syncthreads();

    {
        const int d  = t & 63;
        const int rg = t >> 6;
        float acc[4] = {0.f, 0.f, 0.f, 0.f};
        const float* wrow = ow3 + (size_t)d * NOH;
#pragma unroll 2
        for (int hq = 0; hq < NOH / 4; ++hq) {
            const float4 w = ldg4(wrow + hq * 4);
#pragma unroll
            for (int r = 0; r < 4; ++r) {
                const float4 hv = *reinterpret_cast<const float4*>(&h2[(rg * 4 + r) * NOH + hq * 4]);
                acc[r] += hv.x * w.x + hv.y * w.y + hv.z * w.z + hv.w * w.w;
            }
        }
        const float bias = ob3[d];
#pragma unroll
        for (int r = 0; r < 4; ++r) {
            const int n = n0 + rg * 4 + r;
            const size_t idx = ((size_t)b * NN + n) * ND + d;
            out[idx] = inputs[idx] + acc[r] + bias;
        }
    }
}

extern "C" void kernel_launch(void* const* d_in, const int* in_sizes, int n_in,
                              void* d_out, int out_size, void* d_ws, size_t ws_size,
                              hipStream_t stream)
{
    const float* inputs   = (const float*)d_in[0];
    const float* rel_rec  = (const float*)d_in[1];
    const float* rel_send = (const float*)d_in[2];
    const float* rel_type = (const float*)d_in[3];
    const float* w1  = (const float*)d_in[5];
    const float* b1  = (const float*)d_in[6];
    const float* w2  = (const float*)d_in[7];
    const float* b2  = (const float*)d_in[8];
    const float* w3  = (const float*)d_in[9];
    const float* b3  = (const float*)d_in[10];
    const float* w4  = (const float*)d_in[11];
    const float* b4  = (const float*)d_in[12];
    const float* ow1 = (const float*)d_in[13];
    const float* ob1 = (const float*)d_in[14];
    const float* ow2 = (const float*)d_in[15];
    const float* ob2 = (const float*)d_in[16];
    const float* ow3 = (const float*)d_in[17];
    const float* ob3 = (const float*)d_in[18];

    char* ws = (char*)d_ws;

    k_pre <<<dim3(382), dim3(256), 0, stream>>>(inputs, rel_rec, rel_send,
                                                w1, w3, ws);
    k_edge<<<dim3(512), dim3(512), 0, stream>>>(rel_type,
                                                b1, b2, b3, b4, w2, w4, ws);
    k_out <<<dim3(256), dim3(256), 0, stream>>>((const ushort*)ws, inputs,
                                                ow1, ob1, ow2, ob2, ow3, ob3,
                                                (float*)d_out);
}